// Round 18
// baseline (124.457 us; speedup 1.0000x reference)
//
#include <hip/hip_runtime.h>
#include <hip/hip_fp16.h>

#define N_NODES 50000
#define E_EDGES 800000
#define ET (E_EDGES + N_NODES)
#define NBKT 1024          // padded bucket count (782 used)
#define BCAP 2048          // scratch capacity per bucket
#define SCAP 2112          // BCAP + 64 self-loops
#define CSTR 16            // cursor stride (ints)
#define G1_BLOCKS 391
#define P_BLOCKS 250
#define P_EPB 3200         // 250*3200 = 800,000 edges exactly
#define PB0 (NBKT * CSTR)  // prep index base = 16384

typedef _Float16 h8 __attribute__((ext_vector_type(8)));
typedef float f32x16 __attribute__((ext_vector_type(16)));

__device__ __forceinline__ float lrelu(float v) { return v > 0.f ? v : 0.2f * v; }

// ---------- prep: cursor zero + W1 cvt + w2e build (W2 + as2/ad2 rows + zero pad) + Aw rows ----------
__global__ __launch_bounds__(256) void prep_kernel(const float* __restrict__ W1,
                                                   const float* __restrict__ W2,
                                                   const float* __restrict__ as1,
                                                   const float* __restrict__ ad1,
                                                   const float* __restrict__ as2,
                                                   const float* __restrict__ ad2,
                                                   _Float16* __restrict__ w1h,
                                                   _Float16* __restrict__ w2e,
                                                   int* __restrict__ cursor) {
    int i = blockIdx.x * 256 + threadIdx.x;
    if (i < PB0) {
        cursor[i] = 0;
    } else if (i < PB0 + 4096) {
        int j = (i - PB0) * 8;
#pragma unroll
        for (int t = 0; t < 8; t++) w1h[j + t] = (_Float16)W1[j + t];
    } else if (i < PB0 + 4608) {
        int j = (i - (PB0 + 4096)) * 8;   // w2e rows 0..31 from W2
#pragma unroll
        for (int t = 0; t < 8; t++) w2e[j + t] = (_Float16)W2[j + t];
    } else if (i < PB0 + 5376) {
        int j = (i - (PB0 + 4608)) * 8;
#pragma unroll
        for (int t = 0; t < 8; t++) w1h[136 * 256 + j + t] = (_Float16)0.f;
    } else if (i < PB0 + 7424) {
        int a = i - (PB0 + 5376);  // 0..2047 : Aw rows 128..135 of w1h
        int h = a >> 8, k = a & 255;
        const float* av = (h < 4 ? as1 : ad1) + (h & 3) * 32;
        const float* wb = W1 + (size_t)(h & 3) * 32 * 256 + k;
        float s = 0.f;
#pragma unroll
        for (int c = 0; c < 32; c++) s += av[c] * wb[(size_t)c * 256];
        w1h[(size_t)(128 + h) * 256 + k] = (_Float16)s;
    } else if (i < PB0 + 7680) {
        int a = i - (PB0 + 7424);  // 0..255 : w2e rows 32 (as2.W2) / 33 (ad2.W2)
        int h = a >> 7, k = a & 127;
        const float* av = h ? ad2 : as2;
        float s = 0.f;
#pragma unroll
        for (int c = 0; c < 32; c++) s += av[c] * W2[(size_t)c * 128 + k];
        w2e[(size_t)(32 + h) * 128 + k] = (_Float16)s;
    } else if (i < PB0 + 8160) {
        int j = (i - (PB0 + 7680)) * 8;   // zero w2e rows 34..63
        for (int t = 0; t < 8; t++) w2e[34 * 128 + j + t] = (_Float16)0.f;
    }
}

// ---------- fused: blocks [0,391) = GEMM1 (MFMA); blocks [391,641) = edge partition ----------
__global__ __launch_bounds__(256) void gp_kernel(const float* __restrict__ x,
                                                 const int* __restrict__ ei,
                                                 const _Float16* __restrict__ w1h,
                                                 _Float16* __restrict__ h1h,
                                                 float* __restrict__ asc1,
                                                 float* __restrict__ adc1,
                                                 int* __restrict__ cursor,
                                                 int* __restrict__ scratch) {
    __shared__ int hcnt[NBKT];
    __shared__ int hbase[NBKT];
    int tid = threadIdx.x;
    if (blockIdx.x >= G1_BLOCKS) {
        int b = blockIdx.x - G1_BLOCKS;
#pragma unroll
        for (int u = 0; u < NBKT / 256; u++) hcnt[u * 256 + tid] = 0;
        __syncthreads();
        int e0 = b * P_EPB;
        const int4* s4 = (const int4*)(ei + e0);
        const int4* d4 = (const int4*)(ei + E_EDGES + e0);
        for (int q = tid; q < P_EPB / 4; q += 256) {
            int4 d = d4[q];
            atomicAdd(&hcnt[d.x >> 6], 1);
            atomicAdd(&hcnt[d.y >> 6], 1);
            atomicAdd(&hcnt[d.z >> 6], 1);
            atomicAdd(&hcnt[d.w >> 6], 1);
        }
        __syncthreads();
        int rot = (b * 197) & (NBKT - 1);
#pragma unroll
        for (int u = 0; u < NBKT / 256; u++) {
            int bb = (u * 256 + tid + rot) & (NBKT - 1);
            int c = hcnt[bb];
            hbase[bb] = (c > 0) ? atomicAdd(&cursor[bb * CSTR], c) : 0;
            hcnt[bb] = 0;
        }
        __syncthreads();
        for (int q = tid; q < P_EPB / 4; q += 256) {
            int4 s = s4[q];
            int4 d = d4[q];
            int bk, pos;
            bk = d.x >> 6; pos = hbase[bk] + atomicAdd(&hcnt[bk], 1);
            scratch[(size_t)bk * BCAP + pos] = s.x | ((d.x & 63) << 16);
            bk = d.y >> 6; pos = hbase[bk] + atomicAdd(&hcnt[bk], 1);
            scratch[(size_t)bk * BCAP + pos] = s.y | ((d.y & 63) << 16);
            bk = d.z >> 6; pos = hbase[bk] + atomicAdd(&hcnt[bk], 1);
            scratch[(size_t)bk * BCAP + pos] = s.z | ((d.z & 63) << 16);
            bk = d.w >> 6; pos = hbase[bk] + atomicAdd(&hcnt[bk], 1);
            scratch[(size_t)bk * BCAP + pos] = s.w | ((d.w & 63) << 16);
        }
        return;
    }
    // ----- GEMM1 -----
    int wid = tid >> 6, lane = tid & 63;
    int rbase = blockIdx.x * 128 + wid * 32;
    if (rbase >= N_NODES) return;
    int l31 = lane & 31, l5 = lane >> 5;
    int ar = rbase + l31;
    if (ar > N_NODES - 1) ar = N_NODES - 1;
    const float* ap = x + (size_t)ar * 256 + l5 * 8;
    const _Float16* bp = w1h + (size_t)l31 * 256 + l5 * 8;
    f32x16 acc0 = {}, acc1 = {}, acc2 = {}, acc3 = {}, acc4 = {};
#pragma unroll 4
    for (int ks = 0; ks < 16; ks++) {
        float4 xa = *(const float4*)(ap + ks * 16);
        float4 xb = *(const float4*)(ap + ks * 16 + 4);
        h8 av;
        av[0] = (_Float16)xa.x; av[1] = (_Float16)xa.y;
        av[2] = (_Float16)xa.z; av[3] = (_Float16)xa.w;
        av[4] = (_Float16)xb.x; av[5] = (_Float16)xb.y;
        av[6] = (_Float16)xb.z; av[7] = (_Float16)xb.w;
        h8 b0 = *(const h8*)(bp + ks * 16);
        h8 b1 = *(const h8*)(bp + 32 * 256 + ks * 16);
        h8 b2 = *(const h8*)(bp + 64 * 256 + ks * 16);
        h8 b3 = *(const h8*)(bp + 96 * 256 + ks * 16);
        h8 b4 = *(const h8*)(bp + 128 * 256 + ks * 16);
        acc0 = __builtin_amdgcn_mfma_f32_32x32x16_f16(av, b0, acc0, 0, 0, 0);
        acc1 = __builtin_amdgcn_mfma_f32_32x32x16_f16(av, b1, acc1, 0, 0, 0);
        acc2 = __builtin_amdgcn_mfma_f32_32x32x16_f16(av, b2, acc2, 0, 0, 0);
        acc3 = __builtin_amdgcn_mfma_f32_32x32x16_f16(av, b3, acc3, 0, 0, 0);
        acc4 = __builtin_amdgcn_mfma_f32_32x32x16_f16(av, b4, acc4, 0, 0, 0);
    }
#pragma unroll
    for (int j = 0; j < 16; j++) {
        int row = rbase + (j & 3) + 8 * (j >> 2) + 4 * l5;
        if (row < N_NODES) {
            h1h[(size_t)row * 128 + 0  + l31] = (_Float16)acc0[j];
            h1h[(size_t)row * 128 + 32 + l31] = (_Float16)acc1[j];
            h1h[(size_t)row * 128 + 64 + l31] = (_Float16)acc2[j];
            h1h[(size_t)row * 128 + 96 + l31] = (_Float16)acc3[j];
            float v4 = acc4[j];
            if (l31 < 4) asc1[(size_t)row * 4 + l31] = v4;
            else if (l31 < 8) adc1[(size_t)row * 4 + (l31 - 4)] = v4;
        }
    }
}

// ---------- fused fine + layer-1 aggregation + GEMM2 (h1b tile stays in LDS) ----------
__global__ __launch_bounds__(512) void fa_kernel(const int* __restrict__ scratch,
                                                 const int* __restrict__ cursor,
                                                 const float* __restrict__ asc1,
                                                 const float* __restrict__ adc1,
                                                 const __half* __restrict__ h1h,
                                                 const float* __restrict__ b1,
                                                 const _Float16* __restrict__ w2e,
                                                 int* __restrict__ off,
                                                 int* __restrict__ srcs,
                                                 __half* __restrict__ h2h,
                                                 float* __restrict__ asc2,
                                                 float* __restrict__ adc2) {
    __shared__ int rec[BCAP];
    __shared__ int ssrc[SCAP];
    __shared__ int sp01[SCAP];
    __shared__ int sp23[SCAP];
    __shared__ int fh[64];
    __shared__ int fcur[64];
    __shared__ int lstart[64];
    __shared__ int red[512];
    __shared__ _Float16 h1t[64 * 128];   // 16 KB aggregated tile
    int b = blockIdx.x;
    int tid = threadIdx.x;
    int cnt = cursor[b * CSTR];
    int part = 0;
    for (int i = tid; i < b; i += 512) part += cursor[i * CSTR];
    red[tid] = part;
    if (tid < 64) fh[tid] = 0;
    __syncthreads();
    for (int s = 256; s >= 1; s >>= 1) {
        if (tid < s) red[tid] += red[tid + s];
        __syncthreads();
    }
    int gbase = red[0] + b * 64;
    for (int k = tid; k < cnt; k += 512) {
        int r = scratch[(size_t)b * BCAP + k];
        rec[k] = r;
        atomicAdd(&fh[r >> 16], 1);
    }
    __syncthreads();
    if (tid < 64) {
        int n = b * 64 + tid;
        int v = fh[tid] + ((n < N_NODES) ? 1 : 0);
        int incl = v;
#pragma unroll
        for (int d = 1; d < 64; d <<= 1) {
            int u = __shfl_up(incl, d);
            if (tid >= d) incl += u;
        }
        int excl = incl - v;
        lstart[tid] = excl;
        fcur[tid] = excl + ((n < N_NODES) ? 1 : 0);
        if (n < N_NODES) off[n] = gbase + excl;
    }
    if (b == 781 && tid == 0) off[N_NODES] = ET;
    __syncthreads();
    if (tid < 64) {
        int n = b * 64 + tid;
        if (n < N_NODES) {
            int pos = lstart[tid];
            float4 av = *(const float4*)(asc1 + (size_t)n * 4);
            float4 dv = *(const float4*)(adc1 + (size_t)n * 4);
            __half2 p01 = __floats2half2_rn(__expf(lrelu(av.x + dv.x)), __expf(lrelu(av.y + dv.y)));
            __half2 p23 = __floats2half2_rn(__expf(lrelu(av.z + dv.z)), __expf(lrelu(av.w + dv.w)));
            ssrc[pos] = n;
            sp01[pos] = *(int*)&p01;
            sp23[pos] = *(int*)&p23;
            srcs[gbase + pos] = n;
        }
    }
    for (int k = tid; k < cnt; k += 512) {
        int r = rec[k];
        int src = r & 0xFFFF;
        int fbin = r >> 16;
        int dst = b * 64 + fbin;
        int pos = atomicAdd(&fcur[fbin], 1);
        float4 av = *(const float4*)(asc1 + (size_t)src * 4);
        float4 dv = *(const float4*)(adc1 + (size_t)dst * 4);
        __half2 p01 = __floats2half2_rn(__expf(lrelu(av.x + dv.x)), __expf(lrelu(av.y + dv.y)));
        __half2 p23 = __floats2half2_rn(__expf(lrelu(av.z + dv.z)), __expf(lrelu(av.w + dv.w)));
        ssrc[pos] = src;
        sp01[pos] = *(int*)&p01;
        sp23[pos] = *(int*)&p23;
        srcs[gbase + pos] = src;
    }
    __syncthreads();
    // phase 2: aggregation — wave w handles 8 nodes; result -> LDS tile
    int wid = tid >> 6, lane = tid & 63;
    int hh = lane >> 4;
    const __half2* h1h2 = (const __half2*)h1h;
    float bl0 = b1[2 * lane], bl1 = b1[2 * lane + 1];
    __half2* h1t2 = (__half2*)h1t;
    for (int ln = wid * 8; ln < wid * 8 + 8; ln++) {
        int node = b * 64 + ln;
        if (node >= N_NODES) {
            h1t2[ln * 64 + lane] = __floats2half2_rn(0.f, 0.f);
            continue;
        }
        int s0l = lstart[ln];
        int s1l = fcur[ln];
        float den = 0.f, a0 = 0.f, a1 = 0.f;
        int j = s0l;
        for (; j + 8 <= s1l; j += 8) {
            int src8[8];
            int pv[8];
#pragma unroll
            for (int u = 0; u < 8; u++) {
                src8[u] = ssrc[j + u];
                pv[u] = (hh & 2) ? sp23[j + u] : sp01[j + u];
            }
            __half2 hv[8];
#pragma unroll
            for (int u = 0; u < 8; u++) hv[u] = h1h2[(size_t)src8[u] * 64 + lane];
#pragma unroll
            for (int u = 0; u < 8; u++) {
                union { int u32; __half2 h; } v;
                v.u32 = pv[u];
                float p = __half2float((hh & 1) ? v.h.y : v.h.x);
                float2 f = __half22float2(hv[u]);
                den += p;
                a0 += p * f.x;
                a1 += p * f.y;
            }
        }
        for (; j + 4 <= s1l; j += 4) {
            int src4[4];
            int pv[4];
#pragma unroll
            for (int u = 0; u < 4; u++) {
                src4[u] = ssrc[j + u];
                pv[u] = (hh & 2) ? sp23[j + u] : sp01[j + u];
            }
            __half2 hv[4];
#pragma unroll
            for (int u = 0; u < 4; u++) hv[u] = h1h2[(size_t)src4[u] * 64 + lane];
#pragma unroll
            for (int u = 0; u < 4; u++) {
                union { int u32; __half2 h; } v;
                v.u32 = pv[u];
                float p = __half2float((hh & 1) ? v.h.y : v.h.x);
                float2 f = __half22float2(hv[u]);
                den += p;
                a0 += p * f.x;
                a1 += p * f.y;
            }
        }
        for (; j < s1l; j++) {
            union { int u32; __half2 h; } v;
            v.u32 = (hh & 2) ? sp23[j] : sp01[j];
            float p = __half2float((hh & 1) ? v.h.y : v.h.x);
            float2 f = __half22float2(h1h2[(size_t)ssrc[j] * 64 + lane]);
            den += p;
            a0 += p * f.x;
            a1 += p * f.y;
        }
        float inv = 1.f / (den + 1e-16f);
        float o0 = fmaxf(a0 * inv + bl0, 0.f);
        float o1 = fmaxf(a1 * inv + bl1, 0.f);
        h1t2[ln * 64 + lane] = __floats2half2_rn(o0, o1);
    }
    __syncthreads();
    // phase 3: GEMM2 on the LDS tile — waves 0..3 compute the 4 (32-row x 32-col) tiles of C[64x64]
    if (wid < 4) {
        int tr = wid >> 1;      // tile row half
        int tc = wid & 1;       // tile col half (0: h2 cols 0..31; 1: cols 32/33 = asc2/adc2)
        int l31 = lane & 31, l5 = lane >> 5;
        const _Float16* ap = h1t + (size_t)(tr * 32 + l31) * 128 + l5 * 8;
        const _Float16* bp = w2e + (size_t)(tc * 32 + l31) * 128 + l5 * 8;
        f32x16 acc = {};
#pragma unroll
        for (int ks = 0; ks < 8; ks++) {
            h8 av = *(const h8*)(ap + ks * 16);
            h8 bv = *(const h8*)(bp + ks * 16);
            acc = __builtin_amdgcn_mfma_f32_32x32x16_f16(av, bv, acc, 0, 0, 0);
        }
#pragma unroll
        for (int j = 0; j < 16; j++) {
            int row = tr * 32 + (j & 3) + 8 * (j >> 2) + 4 * l5;
            int node = b * 64 + row;
            if (node < N_NODES) {
                float v = acc[j];
                if (tc == 0) {
                    h2h[(size_t)node * 32 + l31] = __float2half(v);
                } else {
                    if (l31 == 0) asc2[node] = v;
                    else if (l31 == 1) adc2[node] = v;
                }
            }
        }
    }
}

// ---------- Layer-2 aggregation + log_softmax (p2 on the fly, compact srcs) ----------
__global__ __launch_bounds__(256) void agg2_kernel(const __half* __restrict__ h2h,
                                                   const int* __restrict__ srcs,
                                                   const float* __restrict__ asc2,
                                                   const float* __restrict__ adc2,
                                                   const float* __restrict__ b2,
                                                   const int* __restrict__ off,
                                                   float* __restrict__ out) {
    int wid = threadIdx.x >> 6, lane = threadIdx.x & 63;
    int node = blockIdx.x * 4 + wid;
    if (node >= N_NODES) return;
    int g = lane >> 4;
    int li = lane & 15;
    const __half2* h2h2 = (const __half2*)h2h;
    float adv = adc2[node];
    int s0 = off[node], s1 = off[node + 1];
    float den = 0.f, a0 = 0.f, a1 = 0.f;
    int j = s0 + g;
    for (; j + 16 <= s1; j += 16) {
        int s[4];
#pragma unroll
        for (int u = 0; u < 4; u++) s[u] = srcs[j + 4 * u];
        float av[4];
#pragma unroll
        for (int u = 0; u < 4; u++) av[u] = asc2[s[u]];
        __half2 hv[4];
#pragma unroll
        for (int u = 0; u < 4; u++) hv[u] = h2h2[(size_t)s[u] * 16 + li];
#pragma unroll
        for (int u = 0; u < 4; u++) {
            float p = __expf(lrelu(av[u] + adv));
            float2 f = __half22float2(hv[u]);
            den += p;
            a0 += p * f.x;
            a1 += p * f.y;
        }
    }
    for (; j < s1; j += 4) {
        int s = srcs[j];
        float p = __expf(lrelu(asc2[s] + adv));
        float2 f = __half22float2(h2h2[(size_t)s * 16 + li]);
        den += p;
        a0 += p * f.x;
        a1 += p * f.y;
    }
    den += __shfl_xor(den, 16); den += __shfl_xor(den, 32);
    a0 += __shfl_xor(a0, 16);  a0 += __shfl_xor(a0, 32);
    a1 += __shfl_xor(a1, 16);  a1 += __shfl_xor(a1, 32);
    float inv = 1.f / (den + 1e-16f);
    float v0 = a0 * inv + b2[2 * li];
    float v1 = a1 * inv + b2[2 * li + 1];
    float mx = fmaxf(v0, v1);
#pragma unroll
    for (int msk = 8; msk >= 1; msk >>= 1) mx = fmaxf(mx, __shfl_xor(mx, msk));
    float se = __expf(v0 - mx) + __expf(v1 - mx);
#pragma unroll
    for (int msk = 8; msk >= 1; msk >>= 1) se += __shfl_xor(se, msk);
    float lse = mx + __logf(se);
    if (lane < 16) {
        ((float2*)out)[(size_t)node * 16 + li] = make_float2(v0 - lse, v1 - lse);
    }
}

extern "C" void kernel_launch(void* const* d_in, const int* in_sizes, int n_in,
                              void* d_out, int out_size, void* d_ws, size_t ws_size,
                              hipStream_t stream) {
    const float* x   = (const float*)d_in[0];
    const int* ei    = (const int*)d_in[1];
    const float* W1  = (const float*)d_in[2];
    const float* as1 = (const float*)d_in[3];
    const float* ad1 = (const float*)d_in[4];
    const float* b1  = (const float*)d_in[5];
    const float* W2  = (const float*)d_in[6];
    const float* as2 = (const float*)d_in[7];
    const float* ad2 = (const float*)d_in[8];
    const float* b2  = (const float*)d_in[9];
    float* out = (float*)d_out;

    char* base = (char*)d_ws;
    int* cursor   = (int*)base;                         // 65,536
    int* scratch  = (int*)(base + 13600000);            // 8,388,608
    _Float16* w1h = (_Float16*)(base + 30377216);       // 81,920
    _Float16* h1h = (_Float16*)(base + 30467328);       // 12,800,000
    _Float16* w2e = (_Float16*)(base + 43267328);       // 16,384 (ex-h1b region)
    __half* h2h   = (__half*)(base + 56067328);         //  3,200,000
    float* asc1   = (float*)(base + 59267328);          //    800,000
    float* adc1   = (float*)(base + 60067328);          //    800,000
    float* asc2   = (float*)(base + 60867328);          //    200,000
    float* adc2   = (float*)(base + 61067328);          //    200,000
    int* off      = (int*)(base + 61267328);            //    200,004
    int* srcs     = (int*)(base + 61471428);            //  3,400,000

    prep_kernel<<<(PB0 + 8160 + 255) / 256, 256, 0, stream>>>(W1, W2, as1, ad1, as2, ad2, w1h, w2e, cursor);
    gp_kernel<<<G1_BLOCKS + P_BLOCKS, 256, 0, stream>>>(x, ei, w1h, h1h, asc1, adc1, cursor, scratch);
    fa_kernel<<<782, 512, 0, stream>>>(scratch, cursor, asc1, adc1, (const __half*)h1h, b1, w2e,
                                       off, srcs, h2h, asc2, adc2);
    agg2_kernel<<<(N_NODES + 3) / 4, 256, 0, stream>>>(h2h, srcs, asc2, adc2, b2, off, out);
}

// Round 19
// 115.530 us; speedup vs baseline: 1.0773x; 1.0773x over previous
//
#include <hip/hip_runtime.h>
#include <hip/hip_fp16.h>

#define N_NODES 50000
#define E_EDGES 800000
#define ET (E_EDGES + N_NODES)
#define NBKT 1024          // padded bucket count (782 used)
#define BCAP 1536          // scratch capacity per bucket (mean 1024, sigma 32 -> 16 sigma headroom)
#define SCAP 1600          // BCAP + 64 self-loops
#define CSTR 16            // cursor stride (ints)
#define G1_BLOCKS 391
#define P_BLOCKS 250
#define P_EPB 3200         // 250*3200 = 800,000 edges exactly
#define PB0 (NBKT * CSTR)  // prep index base = 16384
#define H1TS 136           // h1t row stride in halves (272 B = 17*16 B: aligned, 4-way banks)

typedef _Float16 h8 __attribute__((ext_vector_type(8)));
typedef float f32x16 __attribute__((ext_vector_type(16)));

__device__ __forceinline__ float lrelu(float v) { return v > 0.f ? v : 0.2f * v; }

// ---------- prep: cursor zero + W1 cvt + w2e build (W2 + as2/ad2 rows + zero pad) + Aw rows ----------
__global__ __launch_bounds__(256) void prep_kernel(const float* __restrict__ W1,
                                                   const float* __restrict__ W2,
                                                   const float* __restrict__ as1,
                                                   const float* __restrict__ ad1,
                                                   const float* __restrict__ as2,
                                                   const float* __restrict__ ad2,
                                                   _Float16* __restrict__ w1h,
                                                   _Float16* __restrict__ w2e,
                                                   int* __restrict__ cursor) {
    int i = blockIdx.x * 256 + threadIdx.x;
    if (i < PB0) {
        cursor[i] = 0;
    } else if (i < PB0 + 4096) {
        int j = (i - PB0) * 8;
#pragma unroll
        for (int t = 0; t < 8; t++) w1h[j + t] = (_Float16)W1[j + t];
    } else if (i < PB0 + 4608) {
        int j = (i - (PB0 + 4096)) * 8;   // w2e rows 0..31 from W2
#pragma unroll
        for (int t = 0; t < 8; t++) w2e[j + t] = (_Float16)W2[j + t];
    } else if (i < PB0 + 5376) {
        int j = (i - (PB0 + 4608)) * 8;
#pragma unroll
        for (int t = 0; t < 8; t++) w1h[136 * 256 + j + t] = (_Float16)0.f;
    } else if (i < PB0 + 7424) {
        int a = i - (PB0 + 5376);  // 0..2047 : Aw rows 128..135 of w1h
        int h = a >> 8, k = a & 255;
        const float* av = (h < 4 ? as1 : ad1) + (h & 3) * 32;
        const float* wb = W1 + (size_t)(h & 3) * 32 * 256 + k;
        float s = 0.f;
#pragma unroll
        for (int c = 0; c < 32; c++) s += av[c] * wb[(size_t)c * 256];
        w1h[(size_t)(128 + h) * 256 + k] = (_Float16)s;
    } else if (i < PB0 + 7680) {
        int a = i - (PB0 + 7424);  // 0..255 : w2e rows 32 (as2.W2) / 33 (ad2.W2)
        int h = a >> 7, k = a & 127;
        const float* av = h ? ad2 : as2;
        float s = 0.f;
#pragma unroll
        for (int c = 0; c < 32; c++) s += av[c] * W2[(size_t)c * 128 + k];
        w2e[(size_t)(32 + h) * 128 + k] = (_Float16)s;
    } else if (i < PB0 + 8160) {
        int j = (i - (PB0 + 7680)) * 8;   // zero w2e rows 34..63
        for (int t = 0; t < 8; t++) w2e[34 * 128 + j + t] = (_Float16)0.f;
    }
}

// ---------- fused: blocks [0,391) = GEMM1 (MFMA); blocks [391,641) = edge partition ----------
__global__ __launch_bounds__(256) void gp_kernel(const float* __restrict__ x,
                                                 const int* __restrict__ ei,
                                                 const _Float16* __restrict__ w1h,
                                                 _Float16* __restrict__ h1h,
                                                 float* __restrict__ asc1,
                                                 float* __restrict__ adc1,
                                                 int* __restrict__ cursor,
                                                 int* __restrict__ scratch) {
    __shared__ int hcnt[NBKT];
    __shared__ int hbase[NBKT];
    int tid = threadIdx.x;
    if (blockIdx.x >= G1_BLOCKS) {
        int b = blockIdx.x - G1_BLOCKS;
#pragma unroll
        for (int u = 0; u < NBKT / 256; u++) hcnt[u * 256 + tid] = 0;
        __syncthreads();
        int e0 = b * P_EPB;
        const int4* s4 = (const int4*)(ei + e0);
        const int4* d4 = (const int4*)(ei + E_EDGES + e0);
        for (int q = tid; q < P_EPB / 4; q += 256) {
            int4 d = d4[q];
            atomicAdd(&hcnt[d.x >> 6], 1);
            atomicAdd(&hcnt[d.y >> 6], 1);
            atomicAdd(&hcnt[d.z >> 6], 1);
            atomicAdd(&hcnt[d.w >> 6], 1);
        }
        __syncthreads();
        int rot = (b * 197) & (NBKT - 1);
#pragma unroll
        for (int u = 0; u < NBKT / 256; u++) {
            int bb = (u * 256 + tid + rot) & (NBKT - 1);
            int c = hcnt[bb];
            hbase[bb] = (c > 0) ? atomicAdd(&cursor[bb * CSTR], c) : 0;
            hcnt[bb] = 0;
        }
        __syncthreads();
        for (int q = tid; q < P_EPB / 4; q += 256) {
            int4 s = s4[q];
            int4 d = d4[q];
            int bk, pos;
            bk = d.x >> 6; pos = hbase[bk] + atomicAdd(&hcnt[bk], 1);
            scratch[(size_t)bk * BCAP + pos] = s.x | ((d.x & 63) << 16);
            bk = d.y >> 6; pos = hbase[bk] + atomicAdd(&hcnt[bk], 1);
            scratch[(size_t)bk * BCAP + pos] = s.y | ((d.y & 63) << 16);
            bk = d.z >> 6; pos = hbase[bk] + atomicAdd(&hcnt[bk], 1);
            scratch[(size_t)bk * BCAP + pos] = s.z | ((d.z & 63) << 16);
            bk = d.w >> 6; pos = hbase[bk] + atomicAdd(&hcnt[bk], 1);
            scratch[(size_t)bk * BCAP + pos] = s.w | ((d.w & 63) << 16);
        }
        return;
    }
    // ----- GEMM1 -----
    int wid = tid >> 6, lane = tid & 63;
    int rbase = blockIdx.x * 128 + wid * 32;
    if (rbase >= N_NODES) return;
    int l31 = lane & 31, l5 = lane >> 5;
    int ar = rbase + l31;
    if (ar > N_NODES - 1) ar = N_NODES - 1;
    const float* ap = x + (size_t)ar * 256 + l5 * 8;
    const _Float16* bp = w1h + (size_t)l31 * 256 + l5 * 8;
    f32x16 acc0 = {}, acc1 = {}, acc2 = {}, acc3 = {}, acc4 = {};
#pragma unroll 4
    for (int ks = 0; ks < 16; ks++) {
        float4 xa = *(const float4*)(ap + ks * 16);
        float4 xb = *(const float4*)(ap + ks * 16 + 4);
        h8 av;
        av[0] = (_Float16)xa.x; av[1] = (_Float16)xa.y;
        av[2] = (_Float16)xa.z; av[3] = (_Float16)xa.w;
        av[4] = (_Float16)xb.x; av[5] = (_Float16)xb.y;
        av[6] = (_Float16)xb.z; av[7] = (_Float16)xb.w;
        h8 b0 = *(const h8*)(bp + ks * 16);
        h8 b1 = *(const h8*)(bp + 32 * 256 + ks * 16);
        h8 b2 = *(const h8*)(bp + 64 * 256 + ks * 16);
        h8 b3 = *(const h8*)(bp + 96 * 256 + ks * 16);
        h8 b4 = *(const h8*)(bp + 128 * 256 + ks * 16);
        acc0 = __builtin_amdgcn_mfma_f32_32x32x16_f16(av, b0, acc0, 0, 0, 0);
        acc1 = __builtin_amdgcn_mfma_f32_32x32x16_f16(av, b1, acc1, 0, 0, 0);
        acc2 = __builtin_amdgcn_mfma_f32_32x32x16_f16(av, b2, acc2, 0, 0, 0);
        acc3 = __builtin_amdgcn_mfma_f32_32x32x16_f16(av, b3, acc3, 0, 0, 0);
        acc4 = __builtin_amdgcn_mfma_f32_32x32x16_f16(av, b4, acc4, 0, 0, 0);
    }
#pragma unroll
    for (int j = 0; j < 16; j++) {
        int row = rbase + (j & 3) + 8 * (j >> 2) + 4 * l5;
        if (row < N_NODES) {
            h1h[(size_t)row * 128 + 0  + l31] = (_Float16)acc0[j];
            h1h[(size_t)row * 128 + 32 + l31] = (_Float16)acc1[j];
            h1h[(size_t)row * 128 + 64 + l31] = (_Float16)acc2[j];
            h1h[(size_t)row * 128 + 96 + l31] = (_Float16)acc3[j];
            float v4 = acc4[j];
            if (l31 < 4) asc1[(size_t)row * 4 + l31] = v4;
            else if (l31 < 8) adc1[(size_t)row * 4 + (l31 - 4)] = v4;
        }
    }
}

// ---------- fused fine + layer-1 aggregation + GEMM2 (h1b tile stays in LDS) ----------
// LDS pool: h1t[64][H1TS] halves; rec (BCAP ints) and red (512 ints) alias into it
// (their live ranges end, with a barrier, before phase 2 writes h1t).
__global__ __launch_bounds__(512) void fa_kernel(const int* __restrict__ scratch,
                                                 const int* __restrict__ cursor,
                                                 const float* __restrict__ asc1,
                                                 const float* __restrict__ adc1,
                                                 const __half* __restrict__ h1h,
                                                 const float* __restrict__ b1,
                                                 const _Float16* __restrict__ w2e,
                                                 int* __restrict__ off,
                                                 int* __restrict__ srcs,
                                                 __half* __restrict__ h2h,
                                                 float* __restrict__ asc2,
                                                 float* __restrict__ adc2) {
    __shared__ alignas(16) int shpool[64 * H1TS / 2];   // 17,408 B
    __shared__ int ssrc[SCAP];
    __shared__ int sp01[SCAP];
    __shared__ int sp23[SCAP];
    __shared__ int fh[64];
    __shared__ int fcur[64];
    __shared__ int lstart[64];
    int* rec = shpool;              // bytes [0, 6144)
    int* red = shpool + 2048;       // bytes [8192, 10240)
    _Float16* h1t = (_Float16*)shpool;
    __half2* h1t2 = (__half2*)shpool;

    int b = blockIdx.x;
    int tid = threadIdx.x;
    int cnt = cursor[b * CSTR];
    int part = 0;
    for (int i = tid; i < b; i += 512) part += cursor[i * CSTR];
    red[tid] = part;
    if (tid < 64) fh[tid] = 0;
    __syncthreads();
    for (int s = 256; s >= 1; s >>= 1) {
        if (tid < s) red[tid] += red[tid + s];
        __syncthreads();
    }
    int gbase = red[0] + b * 64;
    __syncthreads();   // red done before rec region reuse (disjoint bytes, but keep ordered)
    for (int k = tid; k < cnt; k += 512) {
        int r = scratch[(size_t)b * BCAP + k];
        rec[k] = r;
        atomicAdd(&fh[r >> 16], 1);
    }
    __syncthreads();
    if (tid < 64) {
        int n = b * 64 + tid;
        int v = fh[tid] + ((n < N_NODES) ? 1 : 0);
        int incl = v;
#pragma unroll
        for (int d = 1; d < 64; d <<= 1) {
            int u = __shfl_up(incl, d);
            if (tid >= d) incl += u;
        }
        int excl = incl - v;
        lstart[tid] = excl;
        fcur[tid] = excl + ((n < N_NODES) ? 1 : 0);
        if (n < N_NODES) off[n] = gbase + excl;
    }
    if (b == 781 && tid == 0) off[N_NODES] = ET;
    __syncthreads();
    if (tid < 64) {
        int n = b * 64 + tid;
        if (n < N_NODES) {
            int pos = lstart[tid];
            float4 av = *(const float4*)(asc1 + (size_t)n * 4);
            float4 dv = *(const float4*)(adc1 + (size_t)n * 4);
            __half2 p01 = __floats2half2_rn(__expf(lrelu(av.x + dv.x)), __expf(lrelu(av.y + dv.y)));
            __half2 p23 = __floats2half2_rn(__expf(lrelu(av.z + dv.z)), __expf(lrelu(av.w + dv.w)));
            ssrc[pos] = n;
            sp01[pos] = *(int*)&p01;
            sp23[pos] = *(int*)&p23;
            srcs[gbase + pos] = n;
        }
    }
    for (int k = tid; k < cnt; k += 512) {
        int r = rec[k];
        int src = r & 0xFFFF;
        int fbin = r >> 16;
        int dst = b * 64 + fbin;
        int pos = atomicAdd(&fcur[fbin], 1);
        float4 av = *(const float4*)(asc1 + (size_t)src * 4);
        float4 dv = *(const float4*)(adc1 + (size_t)dst * 4);
        __half2 p01 = __floats2half2_rn(__expf(lrelu(av.x + dv.x)), __expf(lrelu(av.y + dv.y)));
        __half2 p23 = __floats2half2_rn(__expf(lrelu(av.z + dv.z)), __expf(lrelu(av.w + dv.w)));
        ssrc[pos] = src;
        sp01[pos] = *(int*)&p01;
        sp23[pos] = *(int*)&p23;
        srcs[gbase + pos] = src;
    }
    __syncthreads();   // rec dead from here; h1t may now be written
    // phase 2: aggregation — wave w handles 8 nodes; result -> LDS tile (stride H1TS/2 half2)
    int wid = tid >> 6, lane = tid & 63;
    int hh = lane >> 4;
    const __half2* h1h2 = (const __half2*)h1h;
    float bl0 = b1[2 * lane], bl1 = b1[2 * lane + 1];
    for (int ln = wid * 8; ln < wid * 8 + 8; ln++) {
        int node = b * 64 + ln;
        if (node >= N_NODES) {
            h1t2[ln * (H1TS / 2) + lane] = __floats2half2_rn(0.f, 0.f);
            continue;
        }
        int s0l = lstart[ln];
        int s1l = fcur[ln];
        float den = 0.f, a0 = 0.f, a1 = 0.f;
        int j = s0l;
        for (; j + 8 <= s1l; j += 8) {
            int src8[8];
            int pv[8];
#pragma unroll
            for (int u = 0; u < 8; u++) {
                src8[u] = ssrc[j + u];
                pv[u] = (hh & 2) ? sp23[j + u] : sp01[j + u];
            }
            __half2 hv[8];
#pragma unroll
            for (int u = 0; u < 8; u++) hv[u] = h1h2[(size_t)src8[u] * 64 + lane];
#pragma unroll
            for (int u = 0; u < 8; u++) {
                union { int u32; __half2 h; } v;
                v.u32 = pv[u];
                float p = __half2float((hh & 1) ? v.h.y : v.h.x);
                float2 f = __half22float2(hv[u]);
                den += p;
                a0 += p * f.x;
                a1 += p * f.y;
            }
        }
        for (; j + 4 <= s1l; j += 4) {
            int src4[4];
            int pv[4];
#pragma unroll
            for (int u = 0; u < 4; u++) {
                src4[u] = ssrc[j + u];
                pv[u] = (hh & 2) ? sp23[j + u] : sp01[j + u];
            }
            __half2 hv[4];
#pragma unroll
            for (int u = 0; u < 4; u++) hv[u] = h1h2[(size_t)src4[u] * 64 + lane];
#pragma unroll
            for (int u = 0; u < 4; u++) {
                union { int u32; __half2 h; } v;
                v.u32 = pv[u];
                float p = __half2float((hh & 1) ? v.h.y : v.h.x);
                float2 f = __half22float2(hv[u]);
                den += p;
                a0 += p * f.x;
                a1 += p * f.y;
            }
        }
        for (; j < s1l; j++) {
            union { int u32; __half2 h; } v;
            v.u32 = (hh & 2) ? sp23[j] : sp01[j];
            float p = __half2float((hh & 1) ? v.h.y : v.h.x);
            float2 f = __half22float2(h1h2[(size_t)ssrc[j] * 64 + lane]);
            den += p;
            a0 += p * f.x;
            a1 += p * f.y;
        }
        float inv = 1.f / (den + 1e-16f);
        float o0 = fmaxf(a0 * inv + bl0, 0.f);
        float o1 = fmaxf(a1 * inv + bl1, 0.f);
        h1t2[ln * (H1TS / 2) + lane] = __floats2half2_rn(o0, o1);
    }
    __syncthreads();
    // phase 3: GEMM2 on the LDS tile — waves 0..3 compute the 4 (32-row x 32-col) tiles
    if (wid < 4) {
        int tr = wid >> 1;      // tile row half
        int tc = wid & 1;       // 0: h2 cols 0..31; 1: cols 32/33 = asc2/adc2
        int l31 = lane & 31, l5 = lane >> 5;
        const _Float16* ap = h1t + (size_t)(tr * 32 + l31) * H1TS + l5 * 8;
        const _Float16* bp = w2e + (size_t)(tc * 32 + l31) * 128 + l5 * 8;
        f32x16 acc = {};
#pragma unroll
        for (int ks = 0; ks < 8; ks++) {
            h8 av = *(const h8*)(ap + ks * 16);
            h8 bv = *(const h8*)(bp + ks * 16);
            acc = __builtin_amdgcn_mfma_f32_32x32x16_f16(av, bv, acc, 0, 0, 0);
        }
#pragma unroll
        for (int j = 0; j < 16; j++) {
            int row = tr * 32 + (j & 3) + 8 * (j >> 2) + 4 * l5;
            int node = b * 64 + row;
            if (node < N_NODES) {
                float v = acc[j];
                if (tc == 0) {
                    h2h[(size_t)node * 32 + l31] = __float2half(v);
                } else {
                    if (l31 == 0) asc2[node] = v;
                    else if (l31 == 1) adc2[node] = v;
                }
            }
        }
    }
}

// ---------- Layer-2 aggregation + log_softmax (p2 on the fly, compact srcs) ----------
__global__ __launch_bounds__(256) void agg2_kernel(const __half* __restrict__ h2h,
                                                   const int* __restrict__ srcs,
                                                   const float* __restrict__ asc2,
                                                   const float* __restrict__ adc2,
                                                   const float* __restrict__ b2,
                                                   const int* __restrict__ off,
                                                   float* __restrict__ out) {
    int wid = threadIdx.x >> 6, lane = threadIdx.x & 63;
    int node = blockIdx.x * 4 + wid;
    if (node >= N_NODES) return;
    int g = lane >> 4;
    int li = lane & 15;
    const __half2* h2h2 = (const __half2*)h2h;
    float adv = adc2[node];
    int s0 = off[node], s1 = off[node + 1];
    float den = 0.f, a0 = 0.f, a1 = 0.f;
    int j = s0 + g;
    for (; j + 16 <= s1; j += 16) {
        int s[4];
#pragma unroll
        for (int u = 0; u < 4; u++) s[u] = srcs[j + 4 * u];
        float av[4];
#pragma unroll
        for (int u = 0; u < 4; u++) av[u] = asc2[s[u]];
        __half2 hv[4];
#pragma unroll
        for (int u = 0; u < 4; u++) hv[u] = h2h2[(size_t)s[u] * 16 + li];
#pragma unroll
        for (int u = 0; u < 4; u++) {
            float p = __expf(lrelu(av[u] + adv));
            float2 f = __half22float2(hv[u]);
            den += p;
            a0 += p * f.x;
            a1 += p * f.y;
        }
    }
    for (; j < s1; j += 4) {
        int s = srcs[j];
        float p = __expf(lrelu(asc2[s] + adv));
        float2 f = __half22float2(h2h2[(size_t)s * 16 + li]);
        den += p;
        a0 += p * f.x;
        a1 += p * f.y;
    }
    den += __shfl_xor(den, 16); den += __shfl_xor(den, 32);
    a0 += __shfl_xor(a0, 16);  a0 += __shfl_xor(a0, 32);
    a1 += __shfl_xor(a1, 16);  a1 += __shfl_xor(a1, 32);
    float inv = 1.f / (den + 1e-16f);
    float v0 = a0 * inv + b2[2 * li];
    float v1 = a1 * inv + b2[2 * li + 1];
    float mx = fmaxf(v0, v1);
#pragma unroll
    for (int msk = 8; msk >= 1; msk >>= 1) mx = fmaxf(mx, __shfl_xor(mx, msk));
    float se = __expf(v0 - mx) + __expf(v1 - mx);
#pragma unroll
    for (int msk = 8; msk >= 1; msk >>= 1) se += __shfl_xor(se, msk);
    float lse = mx + __logf(se);
    if (lane < 16) {
        ((float2*)out)[(size_t)node * 16 + li] = make_float2(v0 - lse, v1 - lse);
    }
}

extern "C" void kernel_launch(void* const* d_in, const int* in_sizes, int n_in,
                              void* d_out, int out_size, void* d_ws, size_t ws_size,
                              hipStream_t stream) {
    const float* x   = (const float*)d_in[0];
    const int* ei    = (const int*)d_in[1];
    const float* W1  = (const float*)d_in[2];
    const float* as1 = (const float*)d_in[3];
    const float* ad1 = (const float*)d_in[4];
    const float* b1  = (const float*)d_in[5];
    const float* W2  = (const float*)d_in[6];
    const float* as2 = (const float*)d_in[7];
    const float* ad2 = (const float*)d_in[8];
    const float* b2  = (const float*)d_in[9];
    float* out = (float*)d_out;

    char* base = (char*)d_ws;
    int* cursor   = (int*)base;                         // 65,536
    int* scratch  = (int*)(base + 13600000);            // 1024*1536*4 = 6,291,456
    _Float16* w1h = (_Float16*)(base + 30377216);       // 81,920
    _Float16* h1h = (_Float16*)(base + 30467328);       // 12,800,000
    _Float16* w2e = (_Float16*)(base + 43267328);       // 16,384
    __half* h2h   = (__half*)(base + 56067328);         //  3,200,000
    float* asc1   = (float*)(base + 59267328);          //    800,000
    float* adc1   = (float*)(base + 60067328);          //    800,000
    float* asc2   = (float*)(base + 60867328);          //    200,000
    float* adc2   = (float*)(base + 61067328);          //    200,000
    int* off      = (int*)(base + 61267328);            //    200,004
    int* srcs     = (int*)(base + 61471428);            //  3,400,000

    prep_kernel<<<(PB0 + 8160 + 255) / 256, 256, 0, stream>>>(W1, W2, as1, ad1, as2, ad2, w1h, w2e, cursor);
    gp_kernel<<<G1_BLOCKS + P_BLOCKS, 256, 0, stream>>>(x, ei, w1h, h1h, asc1, adc1, cursor, scratch);
    fa_kernel<<<782, 512, 0, stream>>>(scratch, cursor, asc1, adc1, (const __half*)h1h, b1, w2e,
                                       off, srcs, h2h, asc2, adc2);
    agg2_kernel<<<(N_NODES + 3) / 4, 256, 0, stream>>>(h2h, srcs, asc2, adc2, b2, off, out);
}